// Round 14
// baseline (190.348 us; speedup 1.0000x reference)
//
#include <hip/hip_runtime.h>
#include <hip/hip_bf16.h>

#define T_DIM 2048
#define N_DIM 128
#define K_DIM 256
#define C_DIM 40
#define SEG 256
#define SEGLEN 8      // T_DIM / SEG
#define GRP 8
#define SEGPERGRP 32  // SEG / GRP

typedef __attribute__((ext_vector_type(8))) short bf16x8;
typedef __attribute__((ext_vector_type(4))) float f32x4v;

__device__ __forceinline__ unsigned pack_bf16(float a, float b) {
    union { float f; unsigned u; } ua, ub;
    ua.f = a; ub.f = b;
    unsigned ra = (ua.u + 0x7FFFu + ((ua.u >> 16) & 1u)) >> 16;
    unsigned rb = (ub.u + 0x7FFFu + ((ub.u >> 16) & 1u)) >> 16;
    return (ra & 0xFFFFu) | (rb << 16);
}

// hardware packed f32->bf16 (RNE)
__device__ __forceinline__ unsigned cvt_pk(float a, float b) {
    unsigned r;
    asm("v_cvt_pk_bf16_f32 %0, %1, %2" : "=v"(r) : "v"(a), "v"(b));
    return r;
}

__device__ __forceinline__ float bf_lo(unsigned u) {
    union { unsigned x; float f; } v; v.x = u << 16; return v.f;
}
__device__ __forceinline__ float bf_hi(unsigned u) {
    union { unsigned x; float f; } v; v.x = u & 0xFFFF0000u; return v.f;
}

__device__ __forceinline__ float fast_tanh(float v) {
    float e = __expf(2.f * v);
    return 1.f - 2.f / (e + 1.f);
}

// ---------------- Phase 1 (R11 exact): y = 5*tanh(xW^T+b) -> bf16 ----------
// Best-measured cold GEMM (~105us). LDS-DMA staging (NT), W in regs,
// per-wave 2x8KB dbuf, counted vmcnt(11)/(8), grid-stride tiles, XCD swizzle.
__global__ __launch_bounds__(256, 2) void k_gemm_tanh(
    const float* __restrict__ x, const float* __restrict__ W,
    const float* __restrict__ b, unsigned* __restrict__ ybf)
{
    __shared__ __align__(16) float shX[4][2][16][128];

    const int tid = threadIdx.x;
    const int lane = tid & 63;
    const int wave = tid >> 6;
    const int lr = lane & 15;
    const int kg = lane >> 4;
    const int bid = blockIdx.x;
    const int sbid = (bid & 7) * 64 + (bid >> 3);   // XCD chunk swizzle
    const int gw = sbid * 4 + wave;                 // 0..2047

    bf16x8 wf[3][8];
    #pragma unroll
    for (int cb = 0; cb < 3; ++cb) {
        #pragma unroll
        for (int kk = 0; kk < 8; ++kk) {
            int rowc = cb * 16 + lr;
            float4 w0 = {0.f, 0.f, 0.f, 0.f}, w1 = {0.f, 0.f, 0.f, 0.f};
            if (rowc < C_DIM) {
                const float* wp = W + rowc * K_DIM + kg * 8 + kk * 32;
                w0 = *reinterpret_cast<const float4*>(wp);
                w1 = *reinterpret_cast<const float4*>(wp + 4);
            }
            union { bf16x8 v; unsigned u[4]; } uw;
            uw.u[0] = pack_bf16(w0.x, w0.y);
            uw.u[1] = pack_bf16(w0.z, w0.w);
            uw.u[2] = pack_bf16(w1.x, w1.y);
            uw.u[3] = pack_bf16(w1.z, w1.w);
            wf[cb][kk] = uw.v;
        }
    }

    float4 bia0 = *reinterpret_cast<const float4*>(b + kg * 4);
    float4 bia1 = *reinterpret_cast<const float4*>(b + 16 + kg * 4);
    float4 bia2 = {0.f, 0.f, 0.f, 0.f};
    if (kg < 2) bia2 = *reinterpret_cast<const float4*>(b + 32 + kg * 4);

    auto stage = [&](int h) {
        size_t tile = (size_t)(h >> 1) * 2048 + gw;
        const char* gbase = reinterpret_cast<const char*>(x)
                          + tile * 16384 + (h & 1) * 512;
        float* lbase = &shX[wave][h & 1][0][0];
        #pragma unroll
        for (int j = 0; j < 8; ++j) {
            int r = 2 * j + (lane >> 5);
            const void* gp = gbase + r * 1024 + (lane & 31) * 16;
            __builtin_amdgcn_global_load_lds(
                (const __attribute__((address_space(1))) void*)gp,
                (__attribute__((address_space(3))) void*)(lbase + j * 256),
                16, 0, 2 /* NT */);
        }
    };

    f32x4v acc0, acc1, acc2;

#define COMPUTE_HALF(KH)                                                          \
    do {                                                                          \
        const char* cX = reinterpret_cast<const char*>(&shX[wave][KH][0][0]);     \
        _Pragma("unroll")                                                         \
        for (int kt = 0; kt < 4; ++kt) {                                          \
            int k0 = kg * 32 + kt * 128;                                          \
            float4 d0 = *reinterpret_cast<const float4*>(cX + lr * 512 + k0);      \
            float4 d1 = *reinterpret_cast<const float4*>(cX + lr * 512 + k0 + 16); \
            union { bf16x8 v; unsigned u[4]; } xf;                                \
            xf.u[0] = cvt_pk(d0.x, d0.y);                                         \
            xf.u[1] = cvt_pk(d0.z, d0.w);                                         \
            xf.u[2] = cvt_pk(d1.x, d1.y);                                         \
            xf.u[3] = cvt_pk(d1.z, d1.w);                                         \
            acc0 = __builtin_amdgcn_mfma_f32_16x16x32_bf16(wf[0][KH * 4 + kt], xf.v, acc0, 0, 0, 0); \
            acc1 = __builtin_amdgcn_mfma_f32_16x16x32_bf16(wf[1][KH * 4 + kt], xf.v, acc1, 0, 0, 0); \
            acc2 = __builtin_amdgcn_mfma_f32_16x16x32_bf16(wf[2][KH * 4 + kt], xf.v, acc2, 0, 0, 0); \
        }                                                                         \
    } while (0)

    stage(0);
    stage(1);

    for (int t = 0; t < 8; ++t) {
        __builtin_amdgcn_sched_barrier(0);
        if (t == 0) asm volatile("s_waitcnt vmcnt(8)" ::: "memory");
        else        asm volatile("s_waitcnt vmcnt(11)" ::: "memory");
        __builtin_amdgcn_sched_barrier(0);
        acc0 = (f32x4v){0.f, 0.f, 0.f, 0.f};
        acc1 = (f32x4v){0.f, 0.f, 0.f, 0.f};
        acc2 = (f32x4v){0.f, 0.f, 0.f, 0.f};
        COMPUTE_HALF(0);
        __builtin_amdgcn_sched_barrier(0);
        if (t < 7) stage(2 * t + 2);

        __builtin_amdgcn_sched_barrier(0);
        if (t < 7) asm volatile("s_waitcnt vmcnt(8)" ::: "memory");
        else       asm volatile("s_waitcnt vmcnt(0)" ::: "memory");
        __builtin_amdgcn_sched_barrier(0);
        COMPUTE_HALF(1);

        size_t row = ((size_t)t * 2048 + gw) * 16 + lr;
        unsigned* yr = ybf + row * 20;
        float o00 = 5.f * fast_tanh(acc0[0] + bia0.x);
        float o01 = 5.f * fast_tanh(acc0[1] + bia0.y);
        float o02 = 5.f * fast_tanh(acc0[2] + bia0.z);
        float o03 = 5.f * fast_tanh(acc0[3] + bia0.w);
        float o10 = 5.f * fast_tanh(acc1[0] + bia1.x);
        float o11 = 5.f * fast_tanh(acc1[1] + bia1.y);
        float o12 = 5.f * fast_tanh(acc1[2] + bia1.z);
        float o13 = 5.f * fast_tanh(acc1[3] + bia1.w);
        uint2 p0, p1;
        p0.x = cvt_pk(o00, o01); p0.y = cvt_pk(o02, o03);
        p1.x = cvt_pk(o10, o11); p1.y = cvt_pk(o12, o13);
        *reinterpret_cast<uint2*>(yr + kg * 2) = p0;
        *reinterpret_cast<uint2*>(yr + 8 + kg * 2) = p1;
        if (kg < 2) {
            float o20 = 5.f * fast_tanh(acc2[0] + bia2.x);
            float o21 = 5.f * fast_tanh(acc2[1] + bia2.y);
            float o22 = 5.f * fast_tanh(acc2[2] + bia2.z);
            float o23 = 5.f * fast_tanh(acc2[3] + bia2.w);
            uint2 p2;
            p2.x = cvt_pk(o20, o21); p2.y = cvt_pk(o22, o23);
            *reinterpret_cast<uint2*>(yr + 16 + kg * 2) = p2;
        }

        __builtin_amdgcn_sched_barrier(0);
        if (t < 7) stage(2 * t + 3);
    }
#undef COMPUTE_HALF
}

// -------- BW PROBE: pure streaming read of x (256MB), no output ------------
// 2048 blocks x 256 thr, lane-linear float4, 8-deep ILP. dur - 137.8us =
// this kernel's time -> direct measurement of achievable READ BW in-harness.
__global__ __launch_bounds__(256) void k_probe(const float4* __restrict__ x4)
{
    size_t i = (size_t)blockIdx.x * 256 + threadIdx.x;   // 524288 threads
    float acc = 0.f;
    #pragma unroll 8
    for (int k = 0; k < 32; ++k) {
        float4 v = x4[i + (size_t)k * 524288];           // 16M float4 total
        acc += v.x + v.y + v.z + v.w;
    }
    asm volatile("" :: "v"(acc));   // keep loads live, no store
}

// ---------------- Phase 2a: per-segment 8x8 transition matrices ------------
__global__ __launch_bounds__(128) void k_seg(
    const unsigned* __restrict__ ybf, float* __restrict__ segv, float* __restrict__ segl)
{
    int tid = blockIdx.x * 128 + threadIdx.x;   // 32768 total
    int n = tid & 127;
    int s = tid >> 7;

    float P[8][8];
    #pragma unroll
    for (int j = 0; j < 8; ++j)
        #pragma unroll
        for (int c = 0; c < 8; ++c) P[j][c] = (j == c) ? 1.f : 0.f;

    for (int st = 0; st < SEGLEN; ++st) {
        int t = s * SEGLEN + st;
        const unsigned* yr = ybf + ((size_t)t * N_DIM + n) * 20;
        float e[40];
        #pragma unroll
        for (int i = 0; i < 5; ++i) {
            uint4 w = reinterpret_cast<const uint4*>(yr)[i];
            e[i * 8 + 0] = __expf(bf_lo(w.x));
            e[i * 8 + 1] = __expf(bf_hi(w.x));
            e[i * 8 + 2] = __expf(bf_lo(w.y));
            e[i * 8 + 3] = __expf(bf_hi(w.y));
            e[i * 8 + 4] = __expf(bf_lo(w.z));
            e[i * 8 + 5] = __expf(bf_hi(w.z));
            e[i * 8 + 6] = __expf(bf_lo(w.w));
            e[i * 8 + 7] = __expf(bf_hi(w.w));
        }
        #pragma unroll
        for (int c = 0; c < 8; ++c) {
            float np[8];
            #pragma unroll
            for (int j = 0; j < 4; ++j) {       // flip: all 8 sources
                float a = 0.f;
                #pragma unroll
                for (int i = 0; i < 8; ++i) a += P[i][c] * e[j * 8 + i];
                np[j] = a;
            }
            #pragma unroll
            for (int j = 0; j < 4; ++j)         // flop: 2 sources
                np[4 + j] = P[j][c] * e[32 + j] + P[4 + j][c] * e[36 + j];
            #pragma unroll
            for (int j = 0; j < 8; ++j) P[j][c] = np[j];
        }
    }
    #pragma unroll
    for (int c = 0; c < 8; ++c) {
        float sum = 0.f;
        #pragma unroll
        for (int j = 0; j < 8; ++j) sum += P[j][c];
        float inv = 1.f / sum;
        #pragma unroll
        for (int j = 0; j < 8; ++j)
            segv[(((size_t)s * 8 + c) * 8 + j) * N_DIM + n] = P[j][c] * inv;
        segl[((size_t)s * 8 + c) * N_DIM + n] = __logf(sum);
    }
}

// ---------------- Phase 2b: combine 32 segments per group ------------------
__global__ __launch_bounds__(128) void k_grp(
    const float* __restrict__ segv, const float* __restrict__ segl,
    float* __restrict__ grpv, float* __restrict__ grpl)
{
    int tid = blockIdx.x * 128 + threadIdx.x;  // 8192 total (64 blocks)
    int n = tid & 127;
    int cc = (tid >> 7) & 7;
    int g = tid >> 10;

    float u[8];
    #pragma unroll
    for (int i = 0; i < 8; ++i) u[i] = (i == cc) ? 1.f : 0.f;
    float logacc = 0.f;

    for (int s = g * SEGPERGRP; s < (g + 1) * SEGPERGRP; ++s) {
        float l[8];
        #pragma unroll
        for (int i = 0; i < 8; ++i) l[i] = segl[((size_t)s * 8 + i) * N_DIM + n];
        float m = l[0];
        #pragma unroll
        for (int i = 1; i < 8; ++i) m = fmaxf(m, l[i]);
        float nu[8] = {0.f, 0.f, 0.f, 0.f, 0.f, 0.f, 0.f, 0.f};
        #pragma unroll
        for (int i = 0; i < 8; ++i) {
            float wi = u[i] * __expf(l[i] - m);
            #pragma unroll
            for (int j = 0; j < 8; ++j)
                nu[j] += wi * segv[(((size_t)s * 8 + i) * 8 + j) * N_DIM + n];
        }
        float sum = 0.f;
        #pragma unroll
        for (int j = 0; j < 8; ++j) sum += nu[j];
        float inv = 1.f / sum;
        #pragma unroll
        for (int j = 0; j < 8; ++j) u[j] = nu[j] * inv;
        logacc += m + __logf(sum);
    }
    #pragma unroll
    for (int j = 0; j < 8; ++j)
        grpv[(((size_t)g * 8 + cc) * 8 + j) * N_DIM + n] = u[j];
    grpl[((size_t)g * 8 + cc) * N_DIM + n] = logacc;
}

// ---------------- Phase 2c: fold 8 groups into logZ/T ----------------------
__global__ void k_fin(const float* __restrict__ grpv, const float* __restrict__ grpl,
                      float* __restrict__ lz)
{
    int n = threadIdx.x;  // 128
    float p[8] = {0.25f, 0.25f, 0.25f, 0.25f, 0.f, 0.f, 0.f, 0.f};
    float logZ = 1.3862943611198906f;  // log(4)

    for (int g = 0; g < GRP; ++g) {
        float l[8];
        #pragma unroll
        for (int i = 0; i < 8; ++i) l[i] = grpl[((size_t)g * 8 + i) * N_DIM + n];
        float m = l[0];
        #pragma unroll
        for (int i = 1; i < 8; ++i) m = fmaxf(m, l[i]);
        float nu[8] = {0.f, 0.f, 0.f, 0.f, 0.f, 0.f, 0.f, 0.f};
        #pragma unroll
        for (int i = 0; i < 8; ++i) {
            float wi = p[i] * __expf(l[i] - m);
            #pragma unroll
            for (int j = 0; j < 8; ++j)
                nu[j] += wi * grpv[(((size_t)g * 8 + i) * 8 + j) * N_DIM + n];
        }
        float sum = 0.f;
        #pragma unroll
        for (int j = 0; j < 8; ++j) sum += nu[j];
        float inv = 1.f / sum;
        #pragma unroll
        for (int j = 0; j < 8; ++j) p[j] = nu[j] * inv;
        logZ += m + __logf(sum);
    }
    lz[n] = logZ * (1.f / (float)T_DIM);
}

// ---------------- Phase 3: out = y(bf16) - logZ[n]/T -----------------------
__global__ __launch_bounds__(256) void k_sub(const unsigned* __restrict__ ybf,
                                             const float* __restrict__ lz,
                                             float* __restrict__ out)
{
    int i = blockIdx.x * 256 + threadIdx.x;   // float4-out index; 2621440 total
    int n = (i / 10) & 127;
    float d = lz[n];
    uint2 w = *reinterpret_cast<const uint2*>(ybf + 2 * (size_t)i);
    float4 v;
    v.x = bf_lo(w.x) - d;
    v.y = bf_hi(w.x) - d;
    v.z = bf_lo(w.y) - d;
    v.w = bf_hi(w.y) - d;
    reinterpret_cast<float4*>(out)[i] = v;
}

extern "C" void kernel_launch(void* const* d_in, const int* in_sizes, int n_in,
                              void* d_out, int out_size, void* d_ws, size_t ws_size,
                              hipStream_t stream) {
    const float* x = (const float*)d_in[0];
    const float* W = (const float*)d_in[1];
    const float* b = (const float*)d_in[2];
    float* out = (float*)d_out;
    float* ws = (float*)d_ws;

    unsigned* ybf = (unsigned*)ws;     // T*N*20 u32  (20MB)
    float* segv = ws + 5242880;        // SEG*8*8*128 = 2,097,152 f32
    float* segl = ws + 7340032;        // SEG*8*128   =   262,144 f32
    float* grpv = ws + 7602176;        // GRP*8*8*128 =    65,536 f32
    float* grpl = ws + 7667712;        // GRP*8*128   =     8,192 f32
    float* lz   = ws + 7675904;        // 128 f32     (total ~30.7 MB)

    k_gemm_tanh<<<512, 256, 0, stream>>>(x, W, b, ybf);
    k_seg<<<256, 128, 0, stream>>>(ybf, segv, segl);
    k_grp<<<64, 128, 0, stream>>>(segv, segl, grpv, grpl);
    k_fin<<<1, 128, 0, stream>>>(grpv, grpl, lz);
    k_sub<<<10240, 256, 0, stream>>>(ybf, lz, out);
    k_probe<<<2048, 256, 0, stream>>>((const float4*)x);   // BW measurement
}

// Round 15
// 143.858 us; speedup vs baseline: 1.3232x; 1.3232x over previous
//
#include <hip/hip_runtime.h>
#include <hip/hip_bf16.h>

#define T_DIM 2048
#define N_DIM 128
#define K_DIM 256
#define C_DIM 40
#define SEG 256
#define SEGLEN 8      // T_DIM / SEG
#define GRP 8
#define SEGPERGRP 32  // SEG / GRP

typedef __attribute__((ext_vector_type(8))) short bf16x8;
typedef __attribute__((ext_vector_type(4))) float f32x4v;

__device__ __forceinline__ unsigned pack_bf16(float a, float b) {
    union { float f; unsigned u; } ua, ub;
    ua.f = a; ub.f = b;
    unsigned ra = (ua.u + 0x7FFFu + ((ua.u >> 16) & 1u)) >> 16;
    unsigned rb = (ub.u + 0x7FFFu + ((ub.u >> 16) & 1u)) >> 16;
    return (ra & 0xFFFFu) | (rb << 16);
}

// hardware packed f32->bf16 (RNE)
__device__ __forceinline__ unsigned cvt_pk(float a, float b) {
    unsigned r;
    asm("v_cvt_pk_bf16_f32 %0, %1, %2" : "=v"(r) : "v"(a), "v"(b));
    return r;
}

__device__ __forceinline__ float bf_lo(unsigned u) {
    union { unsigned x; float f; } v; v.x = u << 16; return v.f;
}
__device__ __forceinline__ float bf_hi(unsigned u) {
    union { unsigned x; float f; } v; v.x = u & 0xFFFF0000u; return v.f;
}

__device__ __forceinline__ float fast_tanh(float v) {
    float e = __expf(2.f * v);
    return 1.f - 2.f / (e + 1.f);
}

// ---------------- Phase 1: y = 5*tanh(x W^T + b) -> bf16 -------------------
// PROBE-PATTERN GEMM (R14 probe measured 4.9 TB/s cold with this read style):
//  - block-cooperative staging: 256 thr x 16 thread-linear float4 loads
//    (each wave-instruction = 1KB contiguous), cvt_pk -> bf16 regs (st[16]).
//  - LDS: bf16 64-row tile, double-buffered 2x32KB. XOR swizzle (r&7)<<4 on
//    16B granularity, both sides.
//  - Lead = one full iteration: loads(i+2) issued at top of iter i, written
//    to LDS in iter i+1. No vmcnt drains anywhere: raw s_barrier with manual
//    lgkmcnt(0) only (NOT __syncthreads, which drains vmcnt(0)).
//  - compute: per kt ONE ds_read_b128 (bf16 direct) + 3 MFMA. W in regs.
__global__ __launch_bounds__(256, 2) void k_gemm_tanh(
    const float* __restrict__ x, const float* __restrict__ W,
    const float* __restrict__ b, unsigned* __restrict__ ybf)
{
    __shared__ __align__(16) uint2 shX[2][64][64];   // [buf][row][8B-slot] = 64KB

    const int tid = threadIdx.x;
    const int lane = tid & 63;
    const int wave = tid >> 6;
    const int lr = lane & 15;
    const int kg = lane >> 4;
    const int bid = blockIdx.x;
    const int sbid = (bid & 7) * 64 + (bid >> 3);    // XCD chunk swizzle
    char* lds = reinterpret_cast<char*>(&shX[0][0][0]);

    // ---- W fragments in registers (one-time; wf[cb][kt] = k kt*32+kg*8..+8)
    bf16x8 wf[3][8];
    #pragma unroll
    for (int cb = 0; cb < 3; ++cb) {
        #pragma unroll
        for (int kk = 0; kk < 8; ++kk) {
            int rowc = cb * 16 + lr;
            float4 w0 = {0.f, 0.f, 0.f, 0.f}, w1 = {0.f, 0.f, 0.f, 0.f};
            if (rowc < C_DIM) {
                const float* wp = W + rowc * K_DIM + kg * 8 + kk * 32;
                w0 = *reinterpret_cast<const float4*>(wp);
                w1 = *reinterpret_cast<const float4*>(wp + 4);
            }
            union { bf16x8 v; unsigned u[4]; } uw;
            uw.u[0] = pack_bf16(w0.x, w0.y);
            uw.u[1] = pack_bf16(w0.z, w0.w);
            uw.u[2] = pack_bf16(w1.x, w1.y);
            uw.u[3] = pack_bf16(w1.z, w1.w);
            wf[cb][kk] = uw.v;
        }
    }

    float4 bia0 = *reinterpret_cast<const float4*>(b + kg * 4);
    float4 bia1 = *reinterpret_cast<const float4*>(b + 16 + kg * 4);
    float4 bia2 = {0.f, 0.f, 0.f, 0.f};
    if (kg < 2) bia2 = *reinterpret_cast<const float4*>(b + 32 + kg * 4);

    const float4* x4 = reinterpret_cast<const float4*>(x);
    uint2 st[16];   // staged bf16 for one tile (this thread's 16 float4)

    // probe-pattern load of tile i (rows (i*512+sbid)*64 ..+64), cvt to bf16
    auto LOADCVT = [&](int i) {
        size_t base = ((size_t)i * 512 + sbid) * 4096;   // float4 units
        float4 v[16];
        #pragma unroll
        for (int j = 0; j < 16; ++j)
            v[j] = x4[base + j * 256 + tid];             // 1KB/wave-instr
        #pragma unroll
        for (int j = 0; j < 16; ++j) {
            st[j].x = cvt_pk(v[j].x, v[j].y);
            st[j].y = cvt_pk(v[j].z, v[j].w);
        }
    };

    // write staged tile into buffer d. thread's j-th piece = row 4j+wave,
    // bf16 cols 4*lane..+3 -> logical bytes lane*8, swizzled ^(r&7)<<4.
    auto WRITE = [&](int d) {
        #pragma unroll
        for (int j = 0; j < 16; ++j) {
            int r = 4 * j + wave;
            char* p = lds + d * 32768 + r * 512 + ((lane * 8) ^ ((r & 7) << 4));
            *reinterpret_cast<uint2*>(p) = st[j];
        }
    };

    for (int i0 = 0; i0 < 1; ++i0) {   // scope
        LOADCVT(0);
        WRITE(0);                      // first fill (one-time vmcnt stall)
        LOADCVT(1);                    // tile 1 in flight across barrier
        asm volatile("s_waitcnt lgkmcnt(0)" ::: "memory");
        __builtin_amdgcn_s_barrier();
        __builtin_amdgcn_sched_barrier(0);
    }

    for (int i = 0; i < 8; ++i) {
        int cur = i & 1;
        if (i < 7) WRITE(cur ^ 1);     // consume st (tile i+1) -> other buf
        if (i < 6) LOADCVT(i + 2);     // refill st; full-iteration lead

        // ---- compute tile i from buf cur ----
        f32x4v acc0 = {0.f, 0.f, 0.f, 0.f};
        f32x4v acc1 = {0.f, 0.f, 0.f, 0.f};
        f32x4v acc2 = {0.f, 0.f, 0.f, 0.f};
        const char* rbase = lds + cur * 32768 + (wave * 16 + lr) * 512;
        const int swz = (lr & 7) << 4;
        #pragma unroll
        for (int kt = 0; kt < 8; ++kt) {
            bf16x8 xf = *reinterpret_cast<const bf16x8*>(
                rbase + ((kt * 64 + kg * 16) ^ swz));
            acc0 = __builtin_amdgcn_mfma_f32_16x16x32_bf16(wf[0][kt], xf, acc0, 0, 0, 0);
            acc1 = __builtin_amdgcn_mfma_f32_16x16x32_bf16(wf[1][kt], xf, acc1, 0, 0, 0);
            acc2 = __builtin_amdgcn_mfma_f32_16x16x32_bf16(wf[2][kt], xf, acc2, 0, 0, 0);
        }

        // ---- epilogue: bias + tanh + bf16 store (D: x-row=lr, c=kg*4+reg)
        size_t row = ((size_t)i * 512 + sbid) * 64 + wave * 16 + lr;
        unsigned* yr = ybf + row * 20;
        float o00 = 5.f * fast_tanh(acc0[0] + bia0.x);
        float o01 = 5.f * fast_tanh(acc0[1] + bia0.y);
        float o02 = 5.f * fast_tanh(acc0[2] + bia0.z);
        float o03 = 5.f * fast_tanh(acc0[3] + bia0.w);
        float o10 = 5.f * fast_tanh(acc1[0] + bia1.x);
        float o11 = 5.f * fast_tanh(acc1[1] + bia1.y);
        float o12 = 5.f * fast_tanh(acc1[2] + bia1.z);
        float o13 = 5.f * fast_tanh(acc1[3] + bia1.w);
        uint2 p0, p1;
        p0.x = cvt_pk(o00, o01); p0.y = cvt_pk(o02, o03);
        p1.x = cvt_pk(o10, o11); p1.y = cvt_pk(o12, o13);
        *reinterpret_cast<uint2*>(yr + kg * 2) = p0;
        *reinterpret_cast<uint2*>(yr + 8 + kg * 2) = p1;
        if (kg < 2) {
            float o20 = 5.f * fast_tanh(acc2[0] + bia2.x);
            float o21 = 5.f * fast_tanh(acc2[1] + bia2.y);
            float o22 = 5.f * fast_tanh(acc2[2] + bia2.z);
            float o23 = 5.f * fast_tanh(acc2[3] + bia2.w);
            uint2 p2;
            p2.x = cvt_pk(o20, o21); p2.y = cvt_pk(o22, o23);
            *reinterpret_cast<uint2*>(yr + 16 + kg * 2) = p2;
        }

        // one barrier per iter: drains LDS ops only (loads stay in flight)
        asm volatile("s_waitcnt lgkmcnt(0)" ::: "memory");
        __builtin_amdgcn_s_barrier();
        __builtin_amdgcn_sched_barrier(0);
    }
}

// ---------------- Phase 2a: per-segment 8x8 transition matrices ------------
__global__ __launch_bounds__(128) void k_seg(
    const unsigned* __restrict__ ybf, float* __restrict__ segv, float* __restrict__ segl)
{
    int tid = blockIdx.x * 128 + threadIdx.x;   // 32768 total
    int n = tid & 127;
    int s = tid >> 7;

    float P[8][8];
    #pragma unroll
    for (int j = 0; j < 8; ++j)
        #pragma unroll
        for (int c = 0; c < 8; ++c) P[j][c] = (j == c) ? 1.f : 0.f;

    for (int st = 0; st < SEGLEN; ++st) {
        int t = s * SEGLEN + st;
        const unsigned* yr = ybf + ((size_t)t * N_DIM + n) * 20;
        float e[40];
        #pragma unroll
        for (int i = 0; i < 5; ++i) {
            uint4 w = reinterpret_cast<const uint4*>(yr)[i];
            e[i * 8 + 0] = __expf(bf_lo(w.x));
            e[i * 8 + 1] = __expf(bf_hi(w.x));
            e[i * 8 + 2] = __expf(bf_lo(w.y));
            e[i * 8 + 3] = __expf(bf_hi(w.y));
            e[i * 8 + 4] = __expf(bf_lo(w.z));
            e[i * 8 + 5] = __expf(bf_hi(w.z));
            e[i * 8 + 6] = __expf(bf_lo(w.w));
            e[i * 8 + 7] = __expf(bf_hi(w.w));
        }
        #pragma unroll
        for (int c = 0; c < 8; ++c) {
            float np[8];
            #pragma unroll
            for (int j = 0; j < 4; ++j) {       // flip: all 8 sources
                float a = 0.f;
                #pragma unroll
                for (int i = 0; i < 8; ++i) a += P[i][c] * e[j * 8 + i];
                np[j] = a;
            }
            #pragma unroll
            for (int j = 0; j < 4; ++j)         // flop: 2 sources
                np[4 + j] = P[j][c] * e[32 + j] + P[4 + j][c] * e[36 + j];
            #pragma unroll
            for (int j = 0; j < 8; ++j) P[j][c] = np[j];
        }
    }
    #pragma unroll
    for (int c = 0; c < 8; ++c) {
        float sum = 0.f;
        #pragma unroll
        for (int j = 0; j < 8; ++j) sum += P[j][c];
        float inv = 1.f / sum;
        #pragma unroll
        for (int j = 0; j < 8; ++j)
            segv[(((size_t)s * 8 + c) * 8 + j) * N_DIM + n] = P[j][c] * inv;
        segl[((size_t)s * 8 + c) * N_DIM + n] = __logf(sum);
    }
}

// ---------------- Phase 2b: combine 32 segments per group ------------------
__global__ __launch_bounds__(128) void k_grp(
    const float* __restrict__ segv, const float* __restrict__ segl,
    float* __restrict__ grpv, float* __restrict__ grpl)
{
    int tid = blockIdx.x * 128 + threadIdx.x;  // 8192 total (64 blocks)
    int n = tid & 127;
    int cc = (tid >> 7) & 7;
    int g = tid >> 10;

    float u[8];
    #pragma unroll
    for (int i = 0; i < 8; ++i) u[i] = (i == cc) ? 1.f : 0.f;
    float logacc = 0.f;

    for (int s = g * SEGPERGRP; s < (g + 1) * SEGPERGRP; ++s) {
        float l[8];
        #pragma unroll
        for (int i = 0; i < 8; ++i) l[i] = segl[((size_t)s * 8 + i) * N_DIM + n];
        float m = l[0];
        #pragma unroll
        for (int i = 1; i < 8; ++i) m = fmaxf(m, l[i]);
        float nu[8] = {0.f, 0.f, 0.f, 0.f, 0.f, 0.f, 0.f, 0.f};
        #pragma unroll
        for (int i = 0; i < 8; ++i) {
            float wi = u[i] * __expf(l[i] - m);
            #pragma unroll
            for (int j = 0; j < 8; ++j)
                nu[j] += wi * segv[(((size_t)s * 8 + i) * 8 + j) * N_DIM + n];
        }
        float sum = 0.f;
        #pragma unroll
        for (int j = 0; j < 8; ++j) sum += nu[j];
        float inv = 1.f / sum;
        #pragma unroll
        for (int j = 0; j < 8; ++j) u[j] = nu[j] * inv;
        logacc += m + __logf(sum);
    }
    #pragma unroll
    for (int j = 0; j < 8; ++j)
        grpv[(((size_t)g * 8 + cc) * 8 + j) * N_DIM + n] = u[j];
    grpl[((size_t)g * 8 + cc) * N_DIM + n] = logacc;
}

// ---------------- Phase 2c: fold 8 groups into logZ/T ----------------------
__global__ void k_fin(const float* __restrict__ grpv, const float* __restrict__ grpl,
                      float* __restrict__ lz)
{
    int n = threadIdx.x;  // 128
    float p[8] = {0.25f, 0.25f, 0.25f, 0.25f, 0.f, 0.f, 0.f, 0.f};
    float logZ = 1.3862943611198906f;  // log(4)

    for (int g = 0; g < GRP; ++g) {
        float l[8];
        #pragma unroll
        for (int i = 0; i < 8; ++i) l[i] = grpl[((size_t)g * 8 + i) * N_DIM + n];
        float m = l[0];
        #pragma unroll
        for (int i = 1; i < 8; ++i) m = fmaxf(m, l[i]);
        float nu[8] = {0.f, 0.f, 0.f, 0.f, 0.f, 0.f, 0.f, 0.f};
        #pragma unroll
        for (int i = 0; i < 8; ++i) {
            float wi = p[i] * __expf(l[i] - m);
            #pragma unroll
            for (int j = 0; j < 8; ++j)
                nu[j] += wi * grpv[(((size_t)g * 8 + i) * 8 + j) * N_DIM + n];
        }
        float sum = 0.f;
        #pragma unroll
        for (int j = 0; j < 8; ++j) sum += nu[j];
        float inv = 1.f / sum;
        #pragma unroll
        for (int j = 0; j < 8; ++j) p[j] = nu[j] * inv;
        logZ += m + __logf(sum);
    }
    lz[n] = logZ * (1.f / (float)T_DIM);
}

// ---------------- Phase 3: out = y(bf16) - logZ[n]/T -----------------------
__global__ __launch_bounds__(256) void k_sub(const unsigned* __restrict__ ybf,
                                             const float* __restrict__ lz,
                                             float* __restrict__ out)
{
    int i = blockIdx.x * 256 + threadIdx.x;   // float4-out index; 2621440 total
    int n = (i / 10) & 127;
    float d = lz[n];
    uint2 w = *reinterpret_cast<const uint2*>(ybf + 2 * (size_t)i);
    float4 v;
    v.x = bf_lo(w.x) - d;
    v.y = bf_hi(w.x) - d;
    v.z = bf_lo(w.y) - d;
    v.w = bf_hi(w.y) - d;
    reinterpret_cast<float4*>(out)[i] = v;
}

extern "C" void kernel_launch(void* const* d_in, const int* in_sizes, int n_in,
                              void* d_out, int out_size, void* d_ws, size_t ws_size,
                              hipStream_t stream) {
    const float* x = (const float*)d_in[0];
    const float* W = (const float*)d_in[1];
    const float* b = (const float*)d_in[2];
    float* out = (float*)d_out;
    float* ws = (float*)d_ws;

    unsigned* ybf = (unsigned*)ws;     // T*N*20 u32  (20MB)
    float* segv = ws + 5242880;        // SEG*8*8*128 = 2,097,152 f32
    float* segl = ws + 7340032;        // SEG*8*128   =   262,144 f32
    float* grpv = ws + 7602176;        // GRP*8*8*128 =    65,536 f32
    float* grpl = ws + 7667712;        // GRP*8*128   =     8,192 f32
    float* lz   = ws + 7675904;        // 128 f32     (total ~30.7 MB)

    k_gemm_tanh<<<512, 256, 0, stream>>>(x, W, b, ybf);
    k_seg<<<256, 128, 0, stream>>>(ybf, segv, segl);
    k_grp<<<64, 128, 0, stream>>>(segv, segl, grpv, grpl);
    k_fin<<<1, 128, 0, stream>>>(grpv, grpl, lz);
    k_sub<<<10240, 256, 0, stream>>>(ybf, lz, out);
}

// Round 16
// 140.273 us; speedup vs baseline: 1.3570x; 1.0256x over previous
//
#include <hip/hip_runtime.h>
#include <hip/hip_bf16.h>

#define T_DIM 2048
#define N_DIM 128
#define K_DIM 256
#define C_DIM 40
#define SEG 256
#define SEGLEN 8      // T_DIM / SEG
#define GRP 8
#define SEGPERGRP 32  // SEG / GRP

typedef __attribute__((ext_vector_type(8))) short bf16x8;
typedef __attribute__((ext_vector_type(4))) float f32x4v;

__device__ __forceinline__ unsigned pack_bf16(float a, float b) {
    union { float f; unsigned u; } ua, ub;
    ua.f = a; ub.f = b;
    unsigned ra = (ua.u + 0x7FFFu + ((ua.u >> 16) & 1u)) >> 16;
    unsigned rb = (ub.u + 0x7FFFu + ((ub.u >> 16) & 1u)) >> 16;
    return (ra & 0xFFFFu) | (rb << 16);
}

// hardware packed f32->bf16 (RNE)
__device__ __forceinline__ unsigned cvt_pk(float a, float b) {
    unsigned r;
    asm("v_cvt_pk_bf16_f32 %0, %1, %2" : "=v"(r) : "v"(a), "v"(b));
    return r;
}

__device__ __forceinline__ float bf_lo(unsigned u) {
    union { unsigned x; float f; } v; v.x = u << 16; return v.f;
}
__device__ __forceinline__ float bf_hi(unsigned u) {
    union { unsigned x; float f; } v; v.x = u & 0xFFFF0000u; return v.f;
}

__device__ __forceinline__ float fast_tanh(float v) {
    float e = __expf(2.f * v);
    return 1.f - 2.f / (e + 1.f);
}

// ---------------- Phase 1: y = 5*tanh(x W^T + b) -> bf16 -------------------
// R15 with the ONE fix it needed: loads and their first register use are
// separated by a FULL iteration. LOAD(i) only issues 16 global_load_dwordx4
// into persistent v[16] (64 VGPR, live across the iteration); CVTWRITE runs
// at the TOP of the next iteration, so the compiler's vmcnt wait lands
// ~700-900cy after issue (compute + epilogue + barrier in between).
// No vmcnt drain in the loop; barrier = lgkmcnt(0) + s_barrier only.
__global__ __launch_bounds__(256, 2) void k_gemm_tanh(
    const float* __restrict__ x, const float* __restrict__ W,
    const float* __restrict__ b, unsigned* __restrict__ ybf)
{
    __shared__ __align__(16) uint2 shX[2][64][64];   // [buf][row][8B-slot] = 64KB

    const int tid = threadIdx.x;
    const int lane = tid & 63;
    const int wave = tid >> 6;
    const int lr = lane & 15;
    const int kg = lane >> 4;
    const int bid = blockIdx.x;
    const int sbid = (bid & 7) * 64 + (bid >> 3);    // XCD chunk swizzle
    char* lds = reinterpret_cast<char*>(&shX[0][0][0]);

    // ---- W fragments in registers (one-time; wf[cb][kt] = k kt*32+kg*8..+8)
    bf16x8 wf[3][8];
    #pragma unroll
    for (int cb = 0; cb < 3; ++cb) {
        #pragma unroll
        for (int kk = 0; kk < 8; ++kk) {
            int rowc = cb * 16 + lr;
            float4 w0 = {0.f, 0.f, 0.f, 0.f}, w1 = {0.f, 0.f, 0.f, 0.f};
            if (rowc < C_DIM) {
                const float* wp = W + rowc * K_DIM + kg * 8 + kk * 32;
                w0 = *reinterpret_cast<const float4*>(wp);
                w1 = *reinterpret_cast<const float4*>(wp + 4);
            }
            union { bf16x8 v; unsigned u[4]; } uw;
            uw.u[0] = pack_bf16(w0.x, w0.y);
            uw.u[1] = pack_bf16(w0.z, w0.w);
            uw.u[2] = pack_bf16(w1.x, w1.y);
            uw.u[3] = pack_bf16(w1.z, w1.w);
            wf[cb][kk] = uw.v;
        }
    }

    float4 bia0 = *reinterpret_cast<const float4*>(b + kg * 4);
    float4 bia1 = *reinterpret_cast<const float4*>(b + 16 + kg * 4);
    float4 bia2 = {0.f, 0.f, 0.f, 0.f};
    if (kg < 2) bia2 = *reinterpret_cast<const float4*>(b + 32 + kg * 4);

    const float4* x4 = reinterpret_cast<const float4*>(x);
    float4 v[16];   // persistent in-flight tile (64 VGPR)

    // issue-only: 16 thread-linear float4 loads of tile i (1KB/wave-instr)
    auto LOAD = [&](int i) {
        size_t base = ((size_t)i * 512 + sbid) * 4096;   // float4 units
        #pragma unroll
        for (int j = 0; j < 16; ++j)
            v[j] = x4[base + j * 256 + tid];
    };

    // consume v (loaded one iteration ago): cvt to bf16 + ds_write to buf d.
    // thread's j-th piece = row 4j+wave, bf16 cols 4*lane..+3.
    auto CVTWRITE = [&](int d) {
        #pragma unroll
        for (int j = 0; j < 16; ++j) {
            int r = 4 * j + wave;
            uint2 s;
            s.x = cvt_pk(v[j].x, v[j].y);
            s.y = cvt_pk(v[j].z, v[j].w);
            char* p = lds + d * 32768 + r * 512 + ((lane * 8) ^ ((r & 7) << 4));
            *reinterpret_cast<uint2*>(p) = s;
        }
    };

    // prologue: tile0 -> buf0 (one-time full-latency stall), tile1 in flight
    LOAD(0);
    CVTWRITE(0);
    LOAD(1);
    asm volatile("s_waitcnt lgkmcnt(0)" ::: "memory");
    __builtin_amdgcn_s_barrier();
    __builtin_amdgcn_sched_barrier(0);

    for (int i = 0; i < 8; ++i) {
        int cur = i & 1;
        if (i < 7) CVTWRITE(cur ^ 1);  // tile i+1 (loads 1 iteration old)
        if (i < 6) LOAD(i + 2);        // issue tile i+2; consumed next iter

        // ---- compute tile i from buf cur ----
        f32x4v acc0 = {0.f, 0.f, 0.f, 0.f};
        f32x4v acc1 = {0.f, 0.f, 0.f, 0.f};
        f32x4v acc2 = {0.f, 0.f, 0.f, 0.f};
        const char* rbase = lds + cur * 32768 + (wave * 16 + lr) * 512;
        const int swz = (lr & 7) << 4;
        #pragma unroll
        for (int kt = 0; kt < 8; ++kt) {
            bf16x8 xf = *reinterpret_cast<const bf16x8*>(
                rbase + ((kt * 64 + kg * 16) ^ swz));
            acc0 = __builtin_amdgcn_mfma_f32_16x16x32_bf16(wf[0][kt], xf, acc0, 0, 0, 0);
            acc1 = __builtin_amdgcn_mfma_f32_16x16x32_bf16(wf[1][kt], xf, acc1, 0, 0, 0);
            acc2 = __builtin_amdgcn_mfma_f32_16x16x32_bf16(wf[2][kt], xf, acc2, 0, 0, 0);
        }

        // ---- epilogue: bias + tanh + bf16 store (D: x-row=lr, c=kg*4+reg)
        size_t row = ((size_t)i * 512 + sbid) * 64 + wave * 16 + lr;
        unsigned* yr = ybf + row * 20;
        float o00 = 5.f * fast_tanh(acc0[0] + bia0.x);
        float o01 = 5.f * fast_tanh(acc0[1] + bia0.y);
        float o02 = 5.f * fast_tanh(acc0[2] + bia0.z);
        float o03 = 5.f * fast_tanh(acc0[3] + bia0.w);
        float o10 = 5.f * fast_tanh(acc1[0] + bia1.x);
        float o11 = 5.f * fast_tanh(acc1[1] + bia1.y);
        float o12 = 5.f * fast_tanh(acc1[2] + bia1.z);
        float o13 = 5.f * fast_tanh(acc1[3] + bia1.w);
        uint2 p0, p1;
        p0.x = cvt_pk(o00, o01); p0.y = cvt_pk(o02, o03);
        p1.x = cvt_pk(o10, o11); p1.y = cvt_pk(o12, o13);
        *reinterpret_cast<uint2*>(yr + kg * 2) = p0;
        *reinterpret_cast<uint2*>(yr + 8 + kg * 2) = p1;
        if (kg < 2) {
            float o20 = 5.f * fast_tanh(acc2[0] + bia2.x);
            float o21 = 5.f * fast_tanh(acc2[1] + bia2.y);
            float o22 = 5.f * fast_tanh(acc2[2] + bia2.z);
            float o23 = 5.f * fast_tanh(acc2[3] + bia2.w);
            uint2 p2;
            p2.x = cvt_pk(o20, o21); p2.y = cvt_pk(o22, o23);
            *reinterpret_cast<uint2*>(yr + 16 + kg * 2) = p2;
        }

        // one barrier per iter: drains LDS ops only (global loads stay live)
        asm volatile("s_waitcnt lgkmcnt(0)" ::: "memory");
        __builtin_amdgcn_s_barrier();
        __builtin_amdgcn_sched_barrier(0);
    }
}

// ---------------- Phase 2a: per-segment 8x8 transition matrices ------------
__global__ __launch_bounds__(128) void k_seg(
    const unsigned* __restrict__ ybf, float* __restrict__ segv, float* __restrict__ segl)
{
    int tid = blockIdx.x * 128 + threadIdx.x;   // 32768 total
    int n = tid & 127;
    int s = tid >> 7;

    float P[8][8];
    #pragma unroll
    for (int j = 0; j < 8; ++j)
        #pragma unroll
        for (int c = 0; c < 8; ++c) P[j][c] = (j == c) ? 1.f : 0.f;

    for (int st = 0; st < SEGLEN; ++st) {
        int t = s * SEGLEN + st;
        const unsigned* yr = ybf + ((size_t)t * N_DIM + n) * 20;
        float e[40];
        #pragma unroll
        for (int i = 0; i < 5; ++i) {
            uint4 w = reinterpret_cast<const uint4*>(yr)[i];
            e[i * 8 + 0] = __expf(bf_lo(w.x));
            e[i * 8 + 1] = __expf(bf_hi(w.x));
            e[i * 8 + 2] = __expf(bf_lo(w.y));
            e[i * 8 + 3] = __expf(bf_hi(w.y));
            e[i * 8 + 4] = __expf(bf_lo(w.z));
            e[i * 8 + 5] = __expf(bf_hi(w.z));
            e[i * 8 + 6] = __expf(bf_lo(w.w));
            e[i * 8 + 7] = __expf(bf_hi(w.w));
        }
        #pragma unroll
        for (int c = 0; c < 8; ++c) {
            float np[8];
            #pragma unroll
            for (int j = 0; j < 4; ++j) {       // flip: all 8 sources
                float a = 0.f;
                #pragma unroll
                for (int i = 0; i < 8; ++i) a += P[i][c] * e[j * 8 + i];
                np[j] = a;
            }
            #pragma unroll
            for (int j = 0; j < 4; ++j)         // flop: 2 sources
                np[4 + j] = P[j][c] * e[32 + j] + P[4 + j][c] * e[36 + j];
            #pragma unroll
            for (int j = 0; j < 8; ++j) P[j][c] = np[j];
        }
    }
    #pragma unroll
    for (int c = 0; c < 8; ++c) {
        float sum = 0.f;
        #pragma unroll
        for (int j = 0; j < 8; ++j) sum += P[j][c];
        float inv = 1.f / sum;
        #pragma unroll
        for (int j = 0; j < 8; ++j)
            segv[(((size_t)s * 8 + c) * 8 + j) * N_DIM + n] = P[j][c] * inv;
        segl[((size_t)s * 8 + c) * N_DIM + n] = __logf(sum);
    }
}

// ---------------- Phase 2b: combine 32 segments per group ------------------
__global__ __launch_bounds__(128) void k_grp(
    const float* __restrict__ segv, const float* __restrict__ segl,
    float* __restrict__ grpv, float* __restrict__ grpl)
{
    int tid = blockIdx.x * 128 + threadIdx.x;  // 8192 total (64 blocks)
    int n = tid & 127;
    int cc = (tid >> 7) & 7;
    int g = tid >> 10;

    float u[8];
    #pragma unroll
    for (int i = 0; i < 8; ++i) u[i] = (i == cc) ? 1.f : 0.f;
    float logacc = 0.f;

    for (int s = g * SEGPERGRP; s < (g + 1) * SEGPERGRP; ++s) {
        float l[8];
        #pragma unroll
        for (int i = 0; i < 8; ++i) l[i] = segl[((size_t)s * 8 + i) * N_DIM + n];
        float m = l[0];
        #pragma unroll
        for (int i = 1; i < 8; ++i) m = fmaxf(m, l[i]);
        float nu[8] = {0.f, 0.f, 0.f, 0.f, 0.f, 0.f, 0.f, 0.f};
        #pragma unroll
        for (int i = 0; i < 8; ++i) {
            float wi = u[i] * __expf(l[i] - m);
            #pragma unroll
            for (int j = 0; j < 8; ++j)
                nu[j] += wi * segv[(((size_t)s * 8 + i) * 8 + j) * N_DIM + n];
        }
        float sum = 0.f;
        #pragma unroll
        for (int j = 0; j < 8; ++j) sum += nu[j];
        float inv = 1.f / sum;
        #pragma unroll
        for (int j = 0; j < 8; ++j) u[j] = nu[j] * inv;
        logacc += m + __logf(sum);
    }
    #pragma unroll
    for (int j = 0; j < 8; ++j)
        grpv[(((size_t)g * 8 + cc) * 8 + j) * N_DIM + n] = u[j];
    grpl[((size_t)g * 8 + cc) * N_DIM + n] = logacc;
}

// ---------------- Phase 2c: fold 8 groups into logZ/T ----------------------
__global__ void k_fin(const float* __restrict__ grpv, const float* __restrict__ grpl,
                      float* __restrict__ lz)
{
    int n = threadIdx.x;  // 128
    float p[8] = {0.25f, 0.25f, 0.25f, 0.25f, 0.f, 0.f, 0.f, 0.f};
    float logZ = 1.3862943611198906f;  // log(4)

    for (int g = 0; g < GRP; ++g) {
        float l[8];
        #pragma unroll
        for (int i = 0; i < 8; ++i) l[i] = grpl[((size_t)g * 8 + i) * N_DIM + n];
        float m = l[0];
        #pragma unroll
        for (int i = 1; i < 8; ++i) m = fmaxf(m, l[i]);
        float nu[8] = {0.f, 0.f, 0.f, 0.f, 0.f, 0.f, 0.f, 0.f};
        #pragma unroll
        for (int i = 0; i < 8; ++i) {
            float wi = p[i] * __expf(l[i] - m);
            #pragma unroll
            for (int j = 0; j < 8; ++j)
                nu[j] += wi * grpv[(((size_t)g * 8 + i) * 8 + j) * N_DIM + n];
        }
        float sum = 0.f;
        #pragma unroll
        for (int j = 0; j < 8; ++j) sum += nu[j];
        float inv = 1.f / sum;
        #pragma unroll
        for (int j = 0; j < 8; ++j) p[j] = nu[j] * inv;
        logZ += m + __logf(sum);
    }
    lz[n] = logZ * (1.f / (float)T_DIM);
}

// ---------------- Phase 3: out = y(bf16) - logZ[n]/T -----------------------
__global__ __launch_bounds__(256) void k_sub(const unsigned* __restrict__ ybf,
                                             const float* __restrict__ lz,
                                             float* __restrict__ out)
{
    int i = blockIdx.x * 256 + threadIdx.x;   // float4-out index; 2621440 total
    int n = (i / 10) & 127;
    float d = lz[n];
    uint2 w = *reinterpret_cast<const uint2*>(ybf + 2 * (size_t)i);
    float4 v;
    v.x = bf_lo(w.x) - d;
    v.y = bf_hi(w.x) - d;
    v.z = bf_lo(w.y) - d;
    v.w = bf_hi(w.y) - d;
    reinterpret_cast<float4*>(out)[i] = v;
}

extern "C" void kernel_launch(void* const* d_in, const int* in_sizes, int n_in,
                              void* d_out, int out_size, void* d_ws, size_t ws_size,
                              hipStream_t stream) {
    const float* x = (const float*)d_in[0];
    const float* W = (const float*)d_in[1];
    const float* b = (const float*)d_in[2];
    float* out = (float*)d_out;
    float* ws = (float*)d_ws;

    unsigned* ybf = (unsigned*)ws;     // T*N*20 u32  (20MB)
    float* segv = ws + 5242880;        // SEG*8*8*128 = 2,097,152 f32
    float* segl = ws + 7340032;        // SEG*8*128   =   262,144 f32
    float* grpv = ws + 7602176;        // GRP*8*8*128 =    65,536 f32
    float* grpl = ws + 7667712;        // GRP*8*128   =     8,192 f32
    float* lz   = ws + 7675904;        // 128 f32     (total ~30.7 MB)

    k_gemm_tanh<<<512, 256, 0, stream>>>(x, W, b, ybf);
    k_seg<<<256, 128, 0, stream>>>(ybf, segv, segl);
    k_grp<<<64, 128, 0, stream>>>(segv, segl, grpv, grpl);
    k_fin<<<1, 128, 0, stream>>>(grpv, grpl, lz);
    k_sub<<<10240, 256, 0, stream>>>(ybf, lz, out);
}